// Round 1
// 598.360 us; speedup vs baseline: 1.0469x; 1.0469x over previous
//
#include <hip/hip_runtime.h>
#include <stdint.h>

typedef __attribute__((ext_vector_type(8))) short short8;
typedef __attribute__((ext_vector_type(8))) unsigned short us8;
typedef __attribute__((ext_vector_type(4))) float f32x4;
typedef __attribute__((ext_vector_type(4))) unsigned short usvec4;

#define B_ 8
#define S_ 1024
#define H_ 32
#define D_ 128
#define NSTEP (S_ / 32)   // 32 key-steps of 32

static __device__ __forceinline__ unsigned short f2bf(float f) {
  uint32_t u = __builtin_bit_cast(uint32_t, f);
  u += 0x7FFFu + ((u >> 16) & 1u);
  return (unsigned short)(u >> 16);
}

// ---------------------------------------------------------------------------
// Pre-pass 1: K,V fp32 -> bf16 in MFMA A-fragment layout, once per launch.
//  Kw[bh][step][f*1024 + tile*512 + lane*8 + j] = K[b,h][step*32+tile*16+(lane&15)][f*32+(lane>>4)*8+j]
//  Vw[bh][step][t*512  + lane*8 + r]            = V[b,h][step*32+(lane>>4)*8+r][t*16+(lane&15)]
// 512 threads per (bh,step); 16B coalesced stores.
// ---------------------------------------------------------------------------
__global__ __launch_bounds__(256)
void kv_pre(const float* __restrict__ Kp, const float* __restrict__ Vp,
            unsigned short* __restrict__ Kw, unsigned short* __restrict__ Vw)
{
  const int flat   = blockIdx.x * 256 + threadIdx.x;
  const int tid2   = flat & 511;
  const int bhstep = flat >> 9;            // 0 .. B*H*NSTEP-1
  const int step   = bhstep & (NSTEP - 1);
  const int bhi    = bhstep >> 5;          // NSTEP == 32
  const int h      = bhi & (H_ - 1);
  const int b      = bhi >> 5;             // H_ == 32

  const size_t strideS = (size_t)H_ * D_;
  const size_t base    = ((size_t)b * S_) * strideS + (size_t)h * D_;
  const size_t dst     = (size_t)bhstep * 4096 + (size_t)tid2 * 8;

  // K fragment
  {
    const int f = tid2 >> 7, tile = (tid2 >> 6) & 1, ln = tid2 & 63;
    const int cc = ln & 15, qd = ln >> 4;
    const float* src = Kp + base + (size_t)(step * 32 + tile * 16 + cc) * strideS + f * 32 + qd * 8;
    float4 a = *(const float4*)src;
    float4 c4 = *(const float4*)(src + 4);
    us8 r;
    r[0] = f2bf(a.x);  r[1] = f2bf(a.y);  r[2] = f2bf(a.z);  r[3] = f2bf(a.w);
    r[4] = f2bf(c4.x); r[5] = f2bf(c4.y); r[6] = f2bf(c4.z); r[7] = f2bf(c4.w);
    *(us8*)(Kw + dst) = r;
  }
  // V^T fragment (transpose via 8 strided scalar loads; lines fully consumed per wave)
  {
    const int t = tid2 >> 6, ln = tid2 & 63;
    const int cv = ln & 15, qv = ln >> 4;
    const float* src = Vp + base + (size_t)(step * 32 + qv * 8) * strideS + t * 16 + cv;
    us8 r;
#pragma unroll
    for (int j = 0; j < 8; ++j) r[j] = f2bf(src[(size_t)j * strideS]);
    *(us8*)(Vw + dst) = r;
  }
}

// ---------------------------------------------------------------------------
// Pre-pass 2: bias -> validity bitmask. Word (b,q,step): bit k = key step*32+k valid.
// ---------------------------------------------------------------------------
__global__ __launch_bounds__(256)
void mask_pre(const float* __restrict__ BiasP, uint32_t* __restrict__ Mw)
{
  const int idx = blockIdx.x * 256 + threadIdx.x;   // (b*S + q)*NSTEP + step
  const float NEGT = -1e37f;
  const float* src = BiasP + (size_t)idx * 32;
  uint32_t mbits = 0;
#pragma unroll
  for (int j = 0; j < 8; ++j) {
    float4 v = *(const float4*)(src + j * 4);
    mbits |= (uint32_t)(v.x > NEGT) << (j * 4 + 0);
    mbits |= (uint32_t)(v.y > NEGT) << (j * 4 + 1);
    mbits |= (uint32_t)(v.z > NEGT) << (j * 4 + 2);
    mbits |= (uint32_t)(v.w > NEGT) << (j * 4 + 3);
  }
  Mw[idx] = mbits;
}

// ---------------------------------------------------------------------------
// Main kernel v2: bf16 K/V fragments staged via global_load_lds (linear,
// conflict-free), bitmask bias, defer-max (THR=8 in log2 domain), cvt_pk
// P-pack, double-buffered LDS (2 barriers/valid step), setprio around MFMA.
// Same verified S^T / P^T-shuffle / O^T structure as the baseline.
// ---------------------------------------------------------------------------
__global__ __launch_bounds__(256, 2)
void fa_fwd2(const float* __restrict__ Qp,
             const unsigned short* __restrict__ Kw,
             const unsigned short* __restrict__ Vw,
             const uint32_t* __restrict__ Mw,
             float* __restrict__ Op)
{
  __shared__ __align__(16) unsigned short klds[2][4096];
  __shared__ __align__(16) unsigned short vlds[2][4096];

  const int tid  = threadIdx.x;
  const int lane = tid & 63;
  const int w    = tid >> 6;
  const int quad = lane >> 4;
  const int c    = lane & 15;

  const int qt = blockIdx.x;
  const int h  = blockIdx.y;
  const int b  = blockIdx.z;
  const int qi = qt * 64 + w * 16 + c;

  const size_t strideS = (size_t)H_ * D_;
  const size_t bh  = ((size_t)b * S_) * strideS + (size_t)h * D_;
  const size_t kvb = (size_t)(b * H_ + h) * ((size_t)NSTEP * 4096);

  // Q fragments (B-operand of S^T): Q[qi][d = 32f + quad*8 + j], fp32 -> bf16 (once)
  short8 qf[4];
  {
    const float* qrow = Qp + bh + (size_t)qi * strideS;
#pragma unroll
    for (int f = 0; f < 4; ++f) {
      float4 a  = *(const float4*)(qrow + f * 32 + quad * 8);
      float4 bv = *(const float4*)(qrow + f * 32 + quad * 8 + 4);
      short8 r;
      r[0] = (short)f2bf(a.x);  r[1] = (short)f2bf(a.y);
      r[2] = (short)f2bf(a.z);  r[3] = (short)f2bf(a.w);
      r[4] = (short)f2bf(bv.x); r[5] = (short)f2bf(bv.y);
      r[6] = (short)f2bf(bv.z); r[7] = (short)f2bf(bv.w);
      qf[f] = r;
    }
  }

  const uint32_t* mrow = Mw + ((size_t)b * S_ + qi) * NSTEP;

  float m  = -INFINITY;
  float ll = 0.f;
  f32x4 acc[8];
#pragma unroll
  for (int t = 0; t < 8; ++t) acc[t] = (f32x4){0.f, 0.f, 0.f, 0.f};

  const float SL2E = 0.08838834764831845f * 1.4426950408889634f; // sm_scale * log2(e)
  int cur = 0;

  for (int st = 0; st < NSTEP; ++st) {
    const uint32_t mw_ = mrow[st];
    const int m0 = (mw_ >> (quad * 4)) & 15;        // tile0 bits for my 4 keys
    const int m1 = (mw_ >> (16 + quad * 4)) & 15;   // tile1 bits
    const int wv = __any(m0 | m1);
    const int bvalid = __syncthreads_or(wv);
    if (!bvalid) continue;   // whole 32-key step masked for every query in block

    // Stage K,V bf16 fragments: pure async copy, linear LDS (lane*16B), no VALU
    {
      const unsigned short* kg = Kw + kvb + (size_t)st * 4096 + w * 1024 + lane * 8;
      const unsigned short* vg = Vw + kvb + (size_t)st * 4096 + w * 1024 + lane * 8;
      unsigned short* kl = &klds[cur][w * 1024];
      unsigned short* vl = &vlds[cur][w * 1024];
#pragma unroll
      for (int i = 0; i < 2; ++i) {
        __builtin_amdgcn_global_load_lds(
            (const __attribute__((address_space(1))) void*)(kg + i * 512),
            (__attribute__((address_space(3))) void*)(kl + i * 512), 16, 0, 0);
        __builtin_amdgcn_global_load_lds(
            (const __attribute__((address_space(1))) void*)(vg + i * 512),
            (__attribute__((address_space(3))) void*)(vl + i * 512), 16, 0, 0);
      }
    }
    __syncthreads();   // drains vmcnt before any wave reads LDS

    if (wv) {
      const unsigned short* kb_ = klds[cur];
      const unsigned short* vb_ = vlds[cur];

      f32x4 st0 = (f32x4){0.f, 0.f, 0.f, 0.f};
      f32x4 st1 = (f32x4){0.f, 0.f, 0.f, 0.f};
      __builtin_amdgcn_s_setprio(1);
#pragma unroll
      for (int f = 0; f < 4; ++f) {
        short8 ka  = *(const short8*)(kb_ + f * 1024 + lane * 8);
        short8 kbt = *(const short8*)(kb_ + f * 1024 + 512 + lane * 8);
        st0 = __builtin_amdgcn_mfma_f32_16x16x32_bf16(ka,  qf[f], st0, 0, 0, 0);
        st1 = __builtin_amdgcn_mfma_f32_16x16x32_bf16(kbt, qf[f], st1, 0, 0, 0);
      }
      __builtin_amdgcn_s_setprio(0);

      // logits in log2 domain; masked -> -inf (bias is exactly {0, -fp32max})
      float x0[4], x1[4];
      float mt = -INFINITY;
#pragma unroll
      for (int r = 0; r < 4; ++r) {
        x0[r] = ((m0 >> r) & 1) ? st0[r] * SL2E : -INFINITY;
        x1[r] = ((m1 >> r) & 1) ? st1[r] * SL2E : -INFINITY;
        mt = fmaxf(mt, fmaxf(x0[r], x1[r]));
      }
      mt = fmaxf(mt, __shfl_xor(mt, 16));
      mt = fmaxf(mt, __shfl_xor(mt, 32));   // per-query tile max

      // defer-max: only rescale when the tile max overtakes running max by >8
      if (!__all(mt <= m + 8.f)) {
        const float mn    = fmaxf(m, mt);
        const float alpha = exp2f(m - mn);
        m = mn;
        ll *= alpha;
#pragma unroll
        for (int t = 0; t < 8; ++t) {
          acc[t][0] *= alpha; acc[t][1] *= alpha;
          acc[t][2] *= alpha; acc[t][3] *= alpha;
        }
      }

      float p0[4], p1[4];
      float lt = 0.f;
#pragma unroll
      for (int r = 0; r < 4; ++r) {
        p0[r] = exp2f(x0[r] - m);   // bounded by 2^8 under defer
        p1[r] = exp2f(x1[r] - m);
        lt += p0[r] + p1[r];
      }
      lt += __shfl_xor(lt, 16);
      lt += __shfl_xor(lt, 32);
      ll += lt;

      // pack P^T to bf16 pairs with HW cvt_pk (lo = src0), then cross-quad shuffles
      int i0, i1, i2, i3;
      asm("v_cvt_pk_bf16_f32 %0, %1, %2" : "=v"(i0) : "v"(p0[0]), "v"(p0[1]));
      asm("v_cvt_pk_bf16_f32 %0, %1, %2" : "=v"(i1) : "v"(p0[2]), "v"(p0[3]));
      asm("v_cvt_pk_bf16_f32 %0, %1, %2" : "=v"(i2) : "v"(p1[0]), "v"(p1[1]));
      asm("v_cvt_pk_bf16_f32 %0, %1, %2" : "=v"(i3) : "v"(p1[2]), "v"(p1[3]));

      const int srcA = ((quad & 1) << 5) + c;
      const int srcB = srcA + 16;
      const int hiT  = quad >> 1;

      int sA, sB, w0, w1, w2, w3;
      sA = __shfl(i0, srcA); sB = __shfl(i2, srcA); w0 = hiT ? sB : sA;
      sA = __shfl(i1, srcA); sB = __shfl(i3, srcA); w1 = hiT ? sB : sA;
      sA = __shfl(i0, srcB); sB = __shfl(i2, srcB); w2 = hiT ? sB : sA;
      sA = __shfl(i1, srcB); sB = __shfl(i3, srcB); w3 = hiT ? sB : sA;

      union { int u[4]; short8 v; } pf;
      pf.u[0] = w0; pf.u[1] = w1; pf.u[2] = w2; pf.u[3] = w3;

      __builtin_amdgcn_s_setprio(1);
#pragma unroll
      for (int t = 0; t < 8; ++t) {
        short8 vf = *(const short8*)(vb_ + t * 512 + lane * 8);
        acc[t] = __builtin_amdgcn_mfma_f32_16x16x32_bf16(vf, pf.v, acc[t], 0, 0, 0);
      }
      __builtin_amdgcn_s_setprio(0);
    }
    cur ^= 1;  // double-buffer: next step's stage targets the other buffer,
               // its leading __syncthreads_or orders the WAR — no trailing barrier
  }

  // epilogue: O[qi][d] = acc / l ; d = t*16 + quad*4 + r — FP32 output, 16B stores
  const float rl = 1.0f / ll;
  float* orow = Op + bh + (size_t)qi * strideS;
#pragma unroll
  for (int t = 0; t < 8; ++t) {
    float4 o;
    o.x = acc[t][0] * rl; o.y = acc[t][1] * rl;
    o.z = acc[t][2] * rl; o.w = acc[t][3] * rl;
    *(float4*)(orow + t * 16 + quad * 4) = o;
  }
}

// ---------------------------------------------------------------------------
// Fallback: the previous verified kernel, used only if ws_size is too small.
// ---------------------------------------------------------------------------
__global__ __launch_bounds__(256, 2)
void fa_fwd(const float* __restrict__ Qp,
            const float* __restrict__ Kp,
            const float* __restrict__ Vp,
            const float* __restrict__ BiasP,
            float* __restrict__ Op)
{
  __shared__ __align__(16) unsigned short klds[32 * 136];
  __shared__ __align__(16) unsigned short vlds[8 * 520];

  const int tid  = threadIdx.x;
  const int lane = tid & 63;
  const int w    = tid >> 6;
  const int quad = lane >> 4;
  const int c    = lane & 15;

  const int qt = blockIdx.x;
  const int h  = blockIdx.y;
  const int b  = blockIdx.z;
  const int qi = qt * 64 + w * 16 + c;

  const size_t strideS = (size_t)H_ * D_;
  const size_t bh = ((size_t)b * S_) * strideS + (size_t)h * D_;

  short8 qf[4];
  {
    const float* qrow = Qp + bh + (size_t)qi * strideS;
#pragma unroll
    for (int f = 0; f < 4; ++f) {
      float4 a  = *(const float4*)(qrow + f * 32 + quad * 8);
      float4 bv = *(const float4*)(qrow + f * 32 + quad * 8 + 4);
      short8 r;
      r[0] = (short)f2bf(a.x);  r[1] = (short)f2bf(a.y);
      r[2] = (short)f2bf(a.z);  r[3] = (short)f2bf(a.w);
      r[4] = (short)f2bf(bv.x); r[5] = (short)f2bf(bv.y);
      r[6] = (short)f2bf(bv.z); r[7] = (short)f2bf(bv.w);
      qf[f] = r;
    }
  }

  const float* brow = BiasP + ((size_t)b * S_ + qi) * S_;
  const float NEGT = -1e37f;

  float m  = -INFINITY;
  float ll = 0.f;
  f32x4 acc[8];
#pragma unroll
  for (int t = 0; t < 8; ++t) acc[t] = (f32x4){0.f, 0.f, 0.f, 0.f};

  const float SL2E = 0.08838834764831845f * 1.4426950408889634f;
  const float L2E  = 1.4426950408889634f;

  for (int ks = 0; ks < S_; ks += 32) {
    float4 b0f = *(const float4*)(brow + ks + quad * 4);
    float4 b1f = *(const float4*)(brow + ks + 16 + quad * 4);
    float b0a[4] = {b0f.x, b0f.y, b0f.z, b0f.w};
    float b1a[4] = {b1f.x, b1f.y, b1f.z, b1f.w};
    int lv = 0;
#pragma unroll
    for (int r = 0; r < 4; ++r) lv |= (b0a[r] > NEGT) | (b1a[r] > NEGT);
    const int wv = __any(lv);
    const int bvalid = __syncthreads_or(wv);
    if (!bvalid) continue;

    {
      const int kk = tid >> 3;
      const int dc = tid & 7;

      const float* krow = Kp + bh + (size_t)(ks + kk) * strideS + dc * 16;
      unsigned short kb16[16];
#pragma unroll
      for (int i = 0; i < 4; ++i) {
        float4 kv = *(const float4*)(krow + i * 4);
        kb16[i*4+0] = f2bf(kv.x); kb16[i*4+1] = f2bf(kv.y);
        kb16[i*4+2] = f2bf(kv.z); kb16[i*4+3] = f2bf(kv.w);
      }
      usvec4* kdst = (usvec4*)(klds + kk * 136 + dc * 16);
#pragma unroll
      for (int i = 0; i < 4; ++i)
        kdst[i] = (usvec4){kb16[i*4+0], kb16[i*4+1], kb16[i*4+2], kb16[i*4+3]};

      const float* vrow = Vp + bh + (size_t)(ks + kk) * strideS + dc * 16;
      const int base = dc * 520 + (kk >> 3) * 128 + (kk & 7);
#pragma unroll
      for (int i = 0; i < 4; ++i) {
        float4 vv = *(const float4*)(vrow + i * 4);
        vlds[base + (i*4+0)*8] = f2bf(vv.x);
        vlds[base + (i*4+1)*8] = f2bf(vv.y);
        vlds[base + (i*4+2)*8] = f2bf(vv.z);
        vlds[base + (i*4+3)*8] = f2bf(vv.w);
      }
    }
    __syncthreads();

    if (wv) {
      f32x4 st0 = (f32x4){0.f, 0.f, 0.f, 0.f};
      f32x4 st1 = (f32x4){0.f, 0.f, 0.f, 0.f};
#pragma unroll
      for (int f = 0; f < 4; ++f) {
        short8 ka = *(const short8*)(klds + c * 136 + f * 32 + quad * 8);
        short8 kb = *(const short8*)(klds + (16 + c) * 136 + f * 32 + quad * 8);
        st0 = __builtin_amdgcn_mfma_f32_16x16x32_bf16(ka, qf[f], st0, 0, 0, 0);
        st1 = __builtin_amdgcn_mfma_f32_16x16x32_bf16(kb, qf[f], st1, 0, 0, 0);
      }

      float x0[4], x1[4];
      float mt = -INFINITY;
#pragma unroll
      for (int r = 0; r < 4; ++r) {
        x0[r] = (b0a[r] > NEGT) ? fmaf(b0a[r], L2E, st0[r] * SL2E) : -INFINITY;
        x1[r] = (b1a[r] > NEGT) ? fmaf(b1a[r], L2E, st1[r] * SL2E) : -INFINITY;
        mt = fmaxf(mt, fmaxf(x0[r], x1[r]));
      }
      mt = fmaxf(mt, __shfl_xor(mt, 16));
      mt = fmaxf(mt, __shfl_xor(mt, 32));
      const float mn    = fmaxf(m, mt);
      const float alpha = exp2f(m - mn);
      m = mn;

      float p0[4], p1[4];
      float lt = 0.f;
#pragma unroll
      for (int r = 0; r < 4; ++r) {
        p0[r] = exp2f(x0[r] - mn);
        p1[r] = exp2f(x1[r] - mn);
        lt += p0[r] + p1[r];
      }
      lt += __shfl_xor(lt, 16);
      lt += __shfl_xor(lt, 32);
      ll = ll * alpha + lt;

#pragma unroll
      for (int t = 0; t < 8; ++t) {
        acc[t][0] *= alpha; acc[t][1] *= alpha;
        acc[t][2] *= alpha; acc[t][3] *= alpha;
      }

      const int i0 = (int)(((uint32_t)f2bf(p0[0])) | ((uint32_t)f2bf(p0[1]) << 16));
      const int i1 = (int)(((uint32_t)f2bf(p0[2])) | ((uint32_t)f2bf(p0[3]) << 16));
      const int i2 = (int)(((uint32_t)f2bf(p1[0])) | ((uint32_t)f2bf(p1[1]) << 16));
      const int i3 = (int)(((uint32_t)f2bf(p1[2])) | ((uint32_t)f2bf(p1[3]) << 16));

      const int srcA = ((quad & 1) << 5) + c;
      const int srcB = srcA + 16;
      const int hiT  = quad >> 1;

      int sA, sB, w0, w1, w2, w3;
      sA = __shfl(i0, srcA); sB = __shfl(i2, srcA); w0 = hiT ? sB : sA;
      sA = __shfl(i1, srcA); sB = __shfl(i3, srcA); w1 = hiT ? sB : sA;
      sA = __shfl(i0, srcB); sB = __shfl(i2, srcB); w2 = hiT ? sB : sA;
      sA = __shfl(i1, srcB); sB = __shfl(i3, srcB); w3 = hiT ? sB : sA;

      union { int u[4]; short8 v; } pf;
      pf.u[0] = w0; pf.u[1] = w1; pf.u[2] = w2; pf.u[3] = w3;

#pragma unroll
      for (int t = 0; t < 8; ++t) {
        short8 vf = *(const short8*)(vlds + t * 520 + lane * 8);
        acc[t] = __builtin_amdgcn_mfma_f32_16x16x32_bf16(vf, pf.v, acc[t], 0, 0, 0);
      }
    }
    __syncthreads();
  }

  const float rl = 1.0f / ll;
  float* orow = Op + bh + (size_t)qi * strideS;
#pragma unroll
  for (int t = 0; t < 8; ++t) {
    float4 o;
    o.x = acc[t][0] * rl; o.y = acc[t][1] * rl;
    o.z = acc[t][2] * rl; o.w = acc[t][3] * rl;
    *(float4*)(orow + t * 16 + quad * 4) = o;
  }
}

extern "C" void kernel_launch(void* const* d_in, const int* in_sizes, int n_in,
                              void* d_out, int out_size, void* d_ws, size_t ws_size,
                              hipStream_t stream) {
  const float* q    = (const float*)d_in[0];
  const float* k    = (const float*)d_in[1];
  const float* v    = (const float*)d_in[2];
  const float* bias = (const float*)d_in[3];
  float* out = (float*)d_out;

  const size_t KW_BYTES = (size_t)B_ * H_ * NSTEP * 4096 * 2;  // 64 MiB (bf16 K frags)
  const size_t MW_BYTES = (size_t)B_ * S_ * NSTEP * 4;         // 1 MiB  (bias bitmask)
  const size_t NEED     = 2 * KW_BYTES + MW_BYTES;

  dim3 grid(S_ / 64, H_, B_);
  if (ws_size >= NEED) {
    unsigned short* Kw = (unsigned short*)d_ws;
    unsigned short* Vw = (unsigned short*)((char*)d_ws + KW_BYTES);
    uint32_t*       Mw = (uint32_t*)((char*)d_ws + 2 * KW_BYTES);
    kv_pre<<<(B_ * H_ * NSTEP * 512) / 256, 256, 0, stream>>>(k, v, Kw, Vw);
    mask_pre<<<(B_ * S_ * NSTEP) / 256, 256, 0, stream>>>(bias, Mw);
    fa_fwd2<<<grid, 256, 0, stream>>>(q, Kw, Vw, Mw, out);
  } else {
    fa_fwd<<<grid, 256, 0, stream>>>(q, k, v, bias, out);
  }
}

// Round 2
// 551.191 us; speedup vs baseline: 1.1364x; 1.0856x over previous
//
#include <hip/hip_runtime.h>
#include <stdint.h>

typedef __attribute__((ext_vector_type(8))) short short8;
typedef __attribute__((ext_vector_type(8))) unsigned short us8;
typedef __attribute__((ext_vector_type(4))) float f32x4;
typedef __attribute__((ext_vector_type(4))) unsigned short usvec4;

#define B_ 8
#define S_ 1024
#define H_ 32
#define D_ 128
#define NSTEP (S_ / 32)   // 32 key-steps of 32

static __device__ __forceinline__ unsigned short f2bf(float f) {
  uint32_t u = __builtin_bit_cast(uint32_t, f);
  u += 0x7FFFu + ((u >> 16) & 1u);
  return (unsigned short)(u >> 16);
}

// ---------------------------------------------------------------------------
// Pre-pass 1 (unchanged, verified): K,V fp32 -> bf16 in MFMA A-fragment layout.
// ---------------------------------------------------------------------------
__global__ __launch_bounds__(256)
void kv_pre(const float* __restrict__ Kp, const float* __restrict__ Vp,
            unsigned short* __restrict__ Kw, unsigned short* __restrict__ Vw)
{
  const int flat   = blockIdx.x * 256 + threadIdx.x;
  const int tid2   = flat & 511;
  const int bhstep = flat >> 9;            // 0 .. B*H*NSTEP-1
  const int step   = bhstep & (NSTEP - 1);
  const int bhi    = bhstep >> 5;          // NSTEP == 32
  const int h      = bhi & (H_ - 1);
  const int b      = bhi >> 5;             // H_ == 32

  const size_t strideS = (size_t)H_ * D_;
  const size_t base    = ((size_t)b * S_) * strideS + (size_t)h * D_;
  const size_t dst     = (size_t)bhstep * 4096 + (size_t)tid2 * 8;

  // K fragment
  {
    const int f = tid2 >> 7, tile = (tid2 >> 6) & 1, ln = tid2 & 63;
    const int cc = ln & 15, qd = ln >> 4;
    const float* src = Kp + base + (size_t)(step * 32 + tile * 16 + cc) * strideS + f * 32 + qd * 8;
    float4 a = *(const float4*)src;
    float4 c4 = *(const float4*)(src + 4);
    us8 r;
    r[0] = f2bf(a.x);  r[1] = f2bf(a.y);  r[2] = f2bf(a.z);  r[3] = f2bf(a.w);
    r[4] = f2bf(c4.x); r[5] = f2bf(c4.y); r[6] = f2bf(c4.z); r[7] = f2bf(c4.w);
    *(us8*)(Kw + dst) = r;
  }
  // V^T fragment (transpose via 8 strided scalar loads; lines fully consumed per wave)
  {
    const int t = tid2 >> 6, ln = tid2 & 63;
    const int cv = ln & 15, qv = ln >> 4;
    const float* src = Vp + base + (size_t)(step * 32 + qv * 8) * strideS + t * 16 + cv;
    us8 r;
#pragma unroll
    for (int j = 0; j < 8; ++j) r[j] = f2bf(src[(size_t)j * strideS]);
    *(us8*)(Vw + dst) = r;
  }
}

// ---------------------------------------------------------------------------
// Pre-pass 2 (unchanged, verified): bias -> validity bitmask.
// ---------------------------------------------------------------------------
__global__ __launch_bounds__(256)
void mask_pre(const float* __restrict__ BiasP, uint32_t* __restrict__ Mw)
{
  const int idx = blockIdx.x * 256 + threadIdx.x;   // (b*S + q)*NSTEP + step
  const float NEGT = -1e37f;
  const float* src = BiasP + (size_t)idx * 32;
  uint32_t mbits = 0;
#pragma unroll
  for (int j = 0; j < 8; ++j) {
    float4 v = *(const float4*)(src + j * 4);
    mbits |= (uint32_t)(v.x > NEGT) << (j * 4 + 0);
    mbits |= (uint32_t)(v.y > NEGT) << (j * 4 + 1);
    mbits |= (uint32_t)(v.z > NEGT) << (j * 4 + 2);
    mbits |= (uint32_t)(v.w > NEGT) << (j * 4 + 3);
  }
  Mw[idx] = mbits;
}

// ---------------------------------------------------------------------------
// Main kernel v3: T3 minimum 2-phase pipeline.
//  - block-valid step mask computed ONCE (wave OR-reduce + LDS atomicOr)
//  - per valid step: {load next mask word; STAGE next step into buf^1;
//    compute current from buf[cur]; s_waitcnt vmcnt(0); raw s_barrier}
//  - ONE barrier per valid step, prefetch latency hidden under compute.
// Compute body (S^T / online softmax / P^T shuffles / O^T PV) unchanged.
// ---------------------------------------------------------------------------
__global__ __launch_bounds__(256, 2)
void fa_fwd2(const float* __restrict__ Qp,
             const unsigned short* __restrict__ Kw,
             const unsigned short* __restrict__ Vw,
             const uint32_t* __restrict__ Mw,
             float* __restrict__ Op)
{
  __shared__ __align__(16) unsigned short klds[2][4096];
  __shared__ __align__(16) unsigned short vlds[2][4096];
  __shared__ uint32_t vmask_sh;

  const int tid  = threadIdx.x;
  const int lane = tid & 63;
  const int w    = tid >> 6;
  const int quad = lane >> 4;
  const int c    = lane & 15;

  const int qt = blockIdx.x;
  const int h  = blockIdx.y;
  const int b  = blockIdx.z;
  const int qi = qt * 64 + w * 16 + c;

  const size_t strideS = (size_t)H_ * D_;
  const size_t bh  = ((size_t)b * S_) * strideS + (size_t)h * D_;
  const size_t kvb = (size_t)(b * H_ + h) * ((size_t)NSTEP * 4096);

  // Q fragments (B-operand of S^T): Q[qi][d = 32f + quad*8 + j], fp32 -> bf16 (once)
  short8 qf[4];
  {
    const float* qrow = Qp + bh + (size_t)qi * strideS;
#pragma unroll
    for (int f = 0; f < 4; ++f) {
      float4 a  = *(const float4*)(qrow + f * 32 + quad * 8);
      float4 bv = *(const float4*)(qrow + f * 32 + quad * 8 + 4);
      short8 r;
      r[0] = (short)f2bf(a.x);  r[1] = (short)f2bf(a.y);
      r[2] = (short)f2bf(a.z);  r[3] = (short)f2bf(a.w);
      r[4] = (short)f2bf(bv.x); r[5] = (short)f2bf(bv.y);
      r[6] = (short)f2bf(bv.z); r[7] = (short)f2bf(bv.w);
      qf[f] = r;
    }
  }

  const uint32_t* mrow = Mw + ((size_t)b * S_ + qi) * NSTEP;

  // --- block-valid step mask, computed once (replaces per-step __syncthreads_or)
  uint32_t myv = 0;
#pragma unroll
  for (int i = 0; i < 8; ++i) {
    uint4 v = *(const uint4*)(mrow + i * 4);
    myv |= (uint32_t)(v.x != 0) << (i * 4 + 0);
    myv |= (uint32_t)(v.y != 0) << (i * 4 + 1);
    myv |= (uint32_t)(v.z != 0) << (i * 4 + 2);
    myv |= (uint32_t)(v.w != 0) << (i * 4 + 3);
  }
  if (tid == 0) vmask_sh = 0;
  __syncthreads();
  {
    uint32_t wor = myv;
#pragma unroll
    for (int d = 1; d < 64; d <<= 1) wor |= __shfl_xor(wor, d);
    if (lane == 0) atomicOr(&vmask_sh, wor);
  }
  __syncthreads();
  const uint32_t bmask = vmask_sh;

  float m  = -INFINITY;
  float ll = 0.f;
  f32x4 acc[8];
#pragma unroll
  for (int t = 0; t < 8; ++t) acc[t] = (f32x4){0.f, 0.f, 0.f, 0.f};

  const float SL2E = 0.08838834764831845f * 1.4426950408889634f; // sm_scale * log2(e)

  auto stage = [&](int bufi, int stp) {
    const unsigned short* kg = Kw + kvb + (size_t)stp * 4096 + w * 1024 + lane * 8;
    const unsigned short* vg = Vw + kvb + (size_t)stp * 4096 + w * 1024 + lane * 8;
    unsigned short* kl = &klds[bufi][w * 1024];
    unsigned short* vl = &vlds[bufi][w * 1024];
    __builtin_amdgcn_global_load_lds(
        (const __attribute__((address_space(1))) void*)kg,
        (__attribute__((address_space(3))) void*)kl, 16, 0, 0);
    __builtin_amdgcn_global_load_lds(
        (const __attribute__((address_space(1))) void*)(kg + 512),
        (__attribute__((address_space(3))) void*)(kl + 512), 16, 0, 0);
    __builtin_amdgcn_global_load_lds(
        (const __attribute__((address_space(1))) void*)vg,
        (__attribute__((address_space(3))) void*)vl, 16, 0, 0);
    __builtin_amdgcn_global_load_lds(
        (const __attribute__((address_space(1))) void*)(vg + 512),
        (__attribute__((address_space(3))) void*)(vl + 512), 16, 0, 0);
  };

  int st  = bmask ? (__ffs(bmask) - 1) : -1;
  int cur = 0;
  uint32_t rem = bmask;
  uint32_t mw_ = 0;

  if (st >= 0) {
    mw_ = mrow[st];
    stage(0, st);
    asm volatile("s_waitcnt vmcnt(0)" ::: "memory");
    __builtin_amdgcn_s_barrier();
    asm volatile("" ::: "memory");
  }

  while (st >= 0) {
    rem &= rem - 1;
    const int nst = rem ? (__ffs(rem) - 1) : -1;

    // next mask word issued BEFORE the prefetch so its vmcnt wait (older) never
    // drains the 4 prefetch loads (newer).
    uint32_t mnxt = 0;
    if (nst >= 0) {
      mnxt = mrow[nst];
      stage(cur ^ 1, nst);   // prefetch next valid step; stays in flight during compute
    }

    const int m0 = (int)((mw_ >> (quad * 4)) & 15u);        // tile0 bits for my 4 keys
    const int m1 = (int)((mw_ >> (16 + quad * 4)) & 15u);   // tile1 bits
    const int wvv = __any(m0 | m1);

    if (wvv) {
      const unsigned short* kb_ = klds[cur];
      const unsigned short* vb_ = vlds[cur];

      f32x4 st0 = (f32x4){0.f, 0.f, 0.f, 0.f};
      f32x4 st1 = (f32x4){0.f, 0.f, 0.f, 0.f};
      __builtin_amdgcn_s_setprio(1);
#pragma unroll
      for (int f = 0; f < 4; ++f) {
        short8 ka  = *(const short8*)(kb_ + f * 1024 + lane * 8);
        short8 kbt = *(const short8*)(kb_ + f * 1024 + 512 + lane * 8);
        st0 = __builtin_amdgcn_mfma_f32_16x16x32_bf16(ka,  qf[f], st0, 0, 0, 0);
        st1 = __builtin_amdgcn_mfma_f32_16x16x32_bf16(kbt, qf[f], st1, 0, 0, 0);
      }
      __builtin_amdgcn_s_setprio(0);

      // logits in log2 domain; masked -> -inf (bias is exactly {0, -fp32max})
      float x0[4], x1[4];
      float mt = -INFINITY;
#pragma unroll
      for (int r = 0; r < 4; ++r) {
        x0[r] = ((m0 >> r) & 1) ? st0[r] * SL2E : -INFINITY;
        x1[r] = ((m1 >> r) & 1) ? st1[r] * SL2E : -INFINITY;
        mt = fmaxf(mt, fmaxf(x0[r], x1[r]));
      }
      mt = fmaxf(mt, __shfl_xor(mt, 16));
      mt = fmaxf(mt, __shfl_xor(mt, 32));   // per-query tile max

      // defer-max: only rescale when the tile max overtakes running max by >8
      if (!__all(mt <= m + 8.f)) {
        const float mn    = fmaxf(m, mt);
        const float alpha = exp2f(m - mn);
        m = mn;
        ll *= alpha;
#pragma unroll
        for (int t = 0; t < 8; ++t) {
          acc[t][0] *= alpha; acc[t][1] *= alpha;
          acc[t][2] *= alpha; acc[t][3] *= alpha;
        }
      }

      float p0[4], p1[4];
      float lt = 0.f;
#pragma unroll
      for (int r = 0; r < 4; ++r) {
        p0[r] = exp2f(x0[r] - m);   // bounded by 2^8 under defer
        p1[r] = exp2f(x1[r] - m);
        lt += p0[r] + p1[r];
      }
      lt += __shfl_xor(lt, 16);
      lt += __shfl_xor(lt, 32);
      ll += lt;

      // pack P^T to bf16 pairs with HW cvt_pk (lo = src0), then cross-quad shuffles
      int i0, i1, i2, i3;
      asm("v_cvt_pk_bf16_f32 %0, %1, %2" : "=v"(i0) : "v"(p0[0]), "v"(p0[1]));
      asm("v_cvt_pk_bf16_f32 %0, %1, %2" : "=v"(i1) : "v"(p0[2]), "v"(p0[3]));
      asm("v_cvt_pk_bf16_f32 %0, %1, %2" : "=v"(i2) : "v"(p1[0]), "v"(p1[1]));
      asm("v_cvt_pk_bf16_f32 %0, %1, %2" : "=v"(i3) : "v"(p1[2]), "v"(p1[3]));

      const int srcA = ((quad & 1) << 5) + c;
      const int srcB = srcA + 16;
      const int hiT  = quad >> 1;

      int sA, sB, w0, w1, w2, w3;
      sA = __shfl(i0, srcA); sB = __shfl(i2, srcA); w0 = hiT ? sB : sA;
      sA = __shfl(i1, srcA); sB = __shfl(i3, srcA); w1 = hiT ? sB : sA;
      sA = __shfl(i0, srcB); sB = __shfl(i2, srcB); w2 = hiT ? sB : sA;
      sA = __shfl(i1, srcB); sB = __shfl(i3, srcB); w3 = hiT ? sB : sA;

      union { int u[4]; short8 v; } pf;
      pf.u[0] = w0; pf.u[1] = w1; pf.u[2] = w2; pf.u[3] = w3;

      __builtin_amdgcn_s_setprio(1);
#pragma unroll
      for (int t = 0; t < 8; ++t) {
        short8 vf = *(const short8*)(vb_ + t * 512 + lane * 8);
        acc[t] = __builtin_amdgcn_mfma_f32_16x16x32_bf16(vf, pf.v, acc[t], 0, 0, 0);
      }
      __builtin_amdgcn_s_setprio(0);
    }

    if (nst >= 0) {
      // single trailing drain+barrier: prefetch completed while we computed;
      // also orders buf reuse (all LDS reads above were lgkm-drained before MFMA).
      asm volatile("s_waitcnt vmcnt(0)" ::: "memory");
      __builtin_amdgcn_s_barrier();
      asm volatile("" ::: "memory");
    }
    cur ^= 1;
    st = nst;
    mw_ = mnxt;
  }

  // epilogue: O[qi][d] = acc / l ; d = t*16 + quad*4 + r — FP32 output, 16B stores
  const float rl = 1.0f / ll;
  float* orow = Op + bh + (size_t)qi * strideS;
#pragma unroll
  for (int t = 0; t < 8; ++t) {
    float4 o;
    o.x = acc[t][0] * rl; o.y = acc[t][1] * rl;
    o.z = acc[t][2] * rl; o.w = acc[t][3] * rl;
    *(float4*)(orow + t * 16 + quad * 4) = o;
  }
}

// ---------------------------------------------------------------------------
// Fallback: previous verified kernel, used only if ws_size is too small.
// ---------------------------------------------------------------------------
__global__ __launch_bounds__(256, 2)
void fa_fwd(const float* __restrict__ Qp,
            const float* __restrict__ Kp,
            const float* __restrict__ Vp,
            const float* __restrict__ BiasP,
            float* __restrict__ Op)
{
  __shared__ __align__(16) unsigned short klds[32 * 136];
  __shared__ __align__(16) unsigned short vlds[8 * 520];

  const int tid  = threadIdx.x;
  const int lane = tid & 63;
  const int w    = tid >> 6;
  const int quad = lane >> 4;
  const int c    = lane & 15;

  const int qt = blockIdx.x;
  const int h  = blockIdx.y;
  const int b  = blockIdx.z;
  const int qi = qt * 64 + w * 16 + c;

  const size_t strideS = (size_t)H_ * D_;
  const size_t bh = ((size_t)b * S_) * strideS + (size_t)h * D_;

  short8 qf[4];
  {
    const float* qrow = Qp + bh + (size_t)qi * strideS;
#pragma unroll
    for (int f = 0; f < 4; ++f) {
      float4 a  = *(const float4*)(qrow + f * 32 + quad * 8);
      float4 bv = *(const float4*)(qrow + f * 32 + quad * 8 + 4);
      short8 r;
      r[0] = (short)f2bf(a.x);  r[1] = (short)f2bf(a.y);
      r[2] = (short)f2bf(a.z);  r[3] = (short)f2bf(a.w);
      r[4] = (short)f2bf(bv.x); r[5] = (short)f2bf(bv.y);
      r[6] = (short)f2bf(bv.z); r[7] = (short)f2bf(bv.w);
      qf[f] = r;
    }
  }

  const float* brow = BiasP + ((size_t)b * S_ + qi) * S_;
  const float NEGT = -1e37f;

  float m  = -INFINITY;
  float ll = 0.f;
  f32x4 acc[8];
#pragma unroll
  for (int t = 0; t < 8; ++t) acc[t] = (f32x4){0.f, 0.f, 0.f, 0.f};

  const float SL2E = 0.08838834764831845f * 1.4426950408889634f;
  const float L2E  = 1.4426950408889634f;

  for (int ks = 0; ks < S_; ks += 32) {
    float4 b0f = *(const float4*)(brow + ks + quad * 4);
    float4 b1f = *(const float4*)(brow + ks + 16 + quad * 4);
    float b0a[4] = {b0f.x, b0f.y, b0f.z, b0f.w};
    float b1a[4] = {b1f.x, b1f.y, b1f.z, b1f.w};
    int lv = 0;
#pragma unroll
    for (int r = 0; r < 4; ++r) lv |= (b0a[r] > NEGT) | (b1a[r] > NEGT);
    const int wv = __any(lv);
    const int bvalid = __syncthreads_or(wv);
    if (!bvalid) continue;

    {
      const int kk = tid >> 3;
      const int dc = tid & 7;

      const float* krow = Kp + bh + (size_t)(ks + kk) * strideS + dc * 16;
      unsigned short kb16[16];
#pragma unroll
      for (int i = 0; i < 4; ++i) {
        float4 kv = *(const float4*)(krow + i * 4);
        kb16[i*4+0] = f2bf(kv.x); kb16[i*4+1] = f2bf(kv.y);
        kb16[i*4+2] = f2bf(kv.z); kb16[i*4+3] = f2bf(kv.w);
      }
      usvec4* kdst = (usvec4*)(klds + kk * 136 + dc * 16);
#pragma unroll
      for (int i = 0; i < 4; ++i)
        kdst[i] = (usvec4){kb16[i*4+0], kb16[i*4+1], kb16[i*4+2], kb16[i*4+3]};

      const float* vrow = Vp + bh + (size_t)(ks + kk) * strideS + dc * 16;
      const int base = dc * 520 + (kk >> 3) * 128 + (kk & 7);
#pragma unroll
      for (int i = 0; i < 4; ++i) {
        float4 vv = *(const float4*)(vrow + i * 4);
        vlds[base + (i*4+0)*8] = f2bf(vv.x);
        vlds[base + (i*4+1)*8] = f2bf(vv.y);
        vlds[base + (i*4+2)*8] = f2bf(vv.z);
        vlds[base + (i*4+3)*8] = f2bf(vv.w);
      }
    }
    __syncthreads();

    if (wv) {
      f32x4 st0 = (f32x4){0.f, 0.f, 0.f, 0.f};
      f32x4 st1 = (f32x4){0.f, 0.f, 0.f, 0.f};
#pragma unroll
      for (int f = 0; f < 4; ++f) {
        short8 ka = *(const short8*)(klds + c * 136 + f * 32 + quad * 8);
        short8 kb = *(const short8*)(klds + (16 + c) * 136 + f * 32 + quad * 8);
        st0 = __builtin_amdgcn_mfma_f32_16x16x32_bf16(ka, qf[f], st0, 0, 0, 0);
        st1 = __builtin_amdgcn_mfma_f32_16x16x32_bf16(kb, qf[f], st1, 0, 0, 0);
      }

      float x0[4], x1[4];
      float mt = -INFINITY;
#pragma unroll
      for (int r = 0; r < 4; ++r) {
        x0[r] = (b0a[r] > NEGT) ? fmaf(b0a[r], L2E, st0[r] * SL2E) : -INFINITY;
        x1[r] = (b1a[r] > NEGT) ? fmaf(b1a[r], L2E, st1[r] * SL2E) : -INFINITY;
        mt = fmaxf(mt, fmaxf(x0[r], x1[r]));
      }
      mt = fmaxf(mt, __shfl_xor(mt, 16));
      mt = fmaxf(mt, __shfl_xor(mt, 32));
      const float mn    = fmaxf(m, mt);
      const float alpha = exp2f(m - mn);
      m = mn;

      float p0[4], p1[4];
      float lt = 0.f;
#pragma unroll
      for (int r = 0; r < 4; ++r) {
        p0[r] = exp2f(x0[r] - mn);
        p1[r] = exp2f(x1[r] - mn);
        lt += p0[r] + p1[r];
      }
      lt += __shfl_xor(lt, 16);
      lt += __shfl_xor(lt, 32);
      ll = ll * alpha + lt;

#pragma unroll
      for (int t = 0; t < 8; ++t) {
        acc[t][0] *= alpha; acc[t][1] *= alpha;
        acc[t][2] *= alpha; acc[t][3] *= alpha;
      }

      const int i0 = (int)(((uint32_t)f2bf(p0[0])) | ((uint32_t)f2bf(p0[1]) << 16));
      const int i1 = (int)(((uint32_t)f2bf(p0[2])) | ((uint32_t)f2bf(p0[3]) << 16));
      const int i2 = (int)(((uint32_t)f2bf(p1[0])) | ((uint32_t)f2bf(p1[1]) << 16));
      const int i3 = (int)(((uint32_t)f2bf(p1[2])) | ((uint32_t)f2bf(p1[3]) << 16));

      const int srcA = ((quad & 1) << 5) + c;
      const int srcB = srcA + 16;
      const int hiT  = quad >> 1;

      int sA, sB, w0, w1, w2, w3;
      sA = __shfl(i0, srcA); sB = __shfl(i2, srcA); w0 = hiT ? sB : sA;
      sA = __shfl(i1, srcA); sB = __shfl(i3, srcA); w1 = hiT ? sB : sA;
      sA = __shfl(i0, srcB); sB = __shfl(i2, srcB); w2 = hiT ? sB : sA;
      sA = __shfl(i1, srcB); sB = __shfl(i3, srcB); w3 = hiT ? sB : sA;

      union { int u[4]; short8 v; } pf;
      pf.u[0] = w0; pf.u[1] = w1; pf.u[2] = w2; pf.u[3] = w3;

#pragma unroll
      for (int t = 0; t < 8; ++t) {
        short8 vf = *(const short8*)(vlds + t * 520 + lane * 8);
        acc[t] = __builtin_amdgcn_mfma_f32_16x16x32_bf16(vf, pf.v, acc[t], 0, 0, 0);
      }
    }
    __syncthreads();
  }

  const float rl = 1.0f / ll;
  float* orow = Op + bh + (size_t)qi * strideS;
#pragma unroll
  for (int t = 0; t < 8; ++t) {
    float4 o;
    o.x = acc[t][0] * rl; o.y = acc[t][1] * rl;
    o.z = acc[t][2] * rl; o.w = acc[t][3] * rl;
    *(float4*)(orow + t * 16 + quad * 4) = o;
  }
}

extern "C" void kernel_launch(void* const* d_in, const int* in_sizes, int n_in,
                              void* d_out, int out_size, void* d_ws, size_t ws_size,
                              hipStream_t stream) {
  const float* q    = (const float*)d_in[0];
  const float* k    = (const float*)d_in[1];
  const float* v    = (const float*)d_in[2];
  const float* bias = (const float*)d_in[3];
  float* out = (float*)d_out;

  const size_t KW_BYTES = (size_t)B_ * H_ * NSTEP * 4096 * 2;  // 64 MiB (bf16 K frags)
  const size_t MW_BYTES = (size_t)B_ * S_ * NSTEP * 4;         // 1 MiB  (bias bitmask)
  const size_t NEED     = 2 * KW_BYTES + MW_BYTES;

  dim3 grid(S_ / 64, H_, B_);
  if (ws_size >= NEED) {
    unsigned short* Kw = (unsigned short*)d_ws;
    unsigned short* Vw = (unsigned short*)((char*)d_ws + KW_BYTES);
    uint32_t*       Mw = (uint32_t*)((char*)d_ws + 2 * KW_BYTES);
    kv_pre<<<(B_ * H_ * NSTEP * 512) / 256, 256, 0, stream>>>(k, v, Kw, Vw);
    mask_pre<<<(B_ * S_ * NSTEP) / 256, 256, 0, stream>>>(bias, Mw);
    fa_fwd2<<<grid, 256, 0, stream>>>(q, Kw, Vw, Mw, out);
  } else {
    fa_fwd<<<grid, 256, 0, stream>>>(q, k, v, bias, out);
  }
}

// Round 3
// 515.585 us; speedup vs baseline: 1.2149x; 1.0691x over previous
//
#include <hip/hip_runtime.h>
#include <stdint.h>

typedef __attribute__((ext_vector_type(8))) short short8;
typedef __attribute__((ext_vector_type(8))) unsigned short us8;
typedef __attribute__((ext_vector_type(4))) float f32x4;
typedef __attribute__((ext_vector_type(4))) unsigned short usvec4;

#define B_ 8
#define S_ 1024
#define H_ 32
#define D_ 128
#define NSTEP (S_ / 32)   // 32 key-steps of 32

static __device__ __forceinline__ unsigned short f2bf(float f) {
  uint32_t u = __builtin_bit_cast(uint32_t, f);
  u += 0x7FFFu + ((u >> 16) & 1u);
  return (unsigned short)(u >> 16);
}

// ---------------------------------------------------------------------------
// Pre-pass 1: bias -> validity bitmask Mw[(b*S+q)*NSTEP+step], PLUS per-(b,step)
// "used by any query" flag Su[b*32+step] (gates kv_pre).
// ---------------------------------------------------------------------------
__global__ __launch_bounds__(256)
void mask_pre(const float* __restrict__ BiasP, uint32_t* __restrict__ Mw,
              uint32_t* __restrict__ Su)
{
  __shared__ uint32_t su_sh[32];
  const int tid = threadIdx.x;
  if (tid < 32) su_sh[tid] = 0;
  __syncthreads();

  const int idx = blockIdx.x * 256 + tid;   // (b*S + q)*NSTEP + step
  const float NEGT = -1e37f;
  const float* src = BiasP + (size_t)idx * 32;
  uint32_t mbits = 0;
#pragma unroll
  for (int j = 0; j < 8; ++j) {
    float4 v = *(const float4*)(src + j * 4);
    mbits |= (uint32_t)(v.x > NEGT) << (j * 4 + 0);
    mbits |= (uint32_t)(v.y > NEGT) << (j * 4 + 1);
    mbits |= (uint32_t)(v.z > NEGT) << (j * 4 + 2);
    mbits |= (uint32_t)(v.w > NEGT) << (j * 4 + 3);
  }
  Mw[idx] = mbits;

  // lanes 0-31 and 32-63 of a wave cover the same 32 steps for 2 queries
  uint32_t used = (mbits != 0) ? 1u : 0u;
  used |= __shfl_xor(used, 32);
  if ((tid & 63) < 32 && used) atomicOr(&su_sh[tid & 31], 1u);
  __syncthreads();
  // block covers 8 queries of one b (32768 idx per b, 256 per block)
  const int b32 = (blockIdx.x >> 7) * 32;
  if (tid < 32 && su_sh[tid]) atomicOr(&Su[b32 + tid], 1u);
}

// ---------------------------------------------------------------------------
// Pre-pass 2: K,V fp32 -> bf16 in MFMA A-fragment layout, gated by Su.
// ---------------------------------------------------------------------------
__global__ __launch_bounds__(256)
void kv_pre(const float* __restrict__ Kp, const float* __restrict__ Vp,
            unsigned short* __restrict__ Kw, unsigned short* __restrict__ Vw,
            const uint32_t* __restrict__ Su)
{
  const int flat   = blockIdx.x * 256 + threadIdx.x;
  const int tid2   = flat & 511;
  const int bhstep = flat >> 9;            // uniform within a 256-thread block
  const int step   = bhstep & (NSTEP - 1);
  const int bhi    = bhstep >> 5;          // NSTEP == 32
  const int h      = bhi & (H_ - 1);
  const int b      = bhi >> 5;             // H_ == 32

  if (!Su[b * 32 + step]) return;          // no query anywhere uses this step

  const size_t strideS = (size_t)H_ * D_;
  const size_t base    = ((size_t)b * S_) * strideS + (size_t)h * D_;
  const size_t dst     = (size_t)bhstep * 4096 + (size_t)tid2 * 8;

  // K fragment
  {
    const int f = tid2 >> 7, tile = (tid2 >> 6) & 1, ln = tid2 & 63;
    const int cc = ln & 15, qd = ln >> 4;
    const float* src = Kp + base + (size_t)(step * 32 + tile * 16 + cc) * strideS + f * 32 + qd * 8;
    float4 a = *(const float4*)src;
    float4 c4 = *(const float4*)(src + 4);
    us8 r;
    r[0] = f2bf(a.x);  r[1] = f2bf(a.y);  r[2] = f2bf(a.z);  r[3] = f2bf(a.w);
    r[4] = f2bf(c4.x); r[5] = f2bf(c4.y); r[6] = f2bf(c4.z); r[7] = f2bf(c4.w);
    *(us8*)(Kw + dst) = r;
  }
  // V^T fragment (transpose via 8 strided scalar loads; lines fully consumed per wave)
  {
    const int t = tid2 >> 6, ln = tid2 & 63;
    const int cv = ln & 15, qv = ln >> 4;
    const float* src = Vp + base + (size_t)(step * 32 + qv * 8) * strideS + t * 16 + cv;
    us8 r;
#pragma unroll
    for (int j = 0; j < 8; ++j) r[j] = f2bf(src[(size_t)j * strideS]);
    *(us8*)(Vw + dst) = r;
  }
}

// ---------------------------------------------------------------------------
// Main kernel v4: 2-phase pipeline + 4 blocks/CU occupancy + deferred ll-reduce.
// ---------------------------------------------------------------------------
__global__ __launch_bounds__(256, 4)
void fa_fwd2(const float* __restrict__ Qp,
             const unsigned short* __restrict__ Kw,
             const unsigned short* __restrict__ Vw,
             const uint32_t* __restrict__ Mw,
             float* __restrict__ Op)
{
  __shared__ __align__(16) unsigned short klds[2][4096];
  __shared__ __align__(16) unsigned short vlds[2][4096];
  __shared__ uint32_t vmask_sh;

  const int tid  = threadIdx.x;
  const int lane = tid & 63;
  const int w    = tid >> 6;
  const int quad = lane >> 4;
  const int c    = lane & 15;

  const int qt = blockIdx.x;
  const int h  = blockIdx.y;
  const int b  = blockIdx.z;
  const int qi = qt * 64 + w * 16 + c;

  const size_t strideS = (size_t)H_ * D_;
  const size_t bh  = ((size_t)b * S_) * strideS + (size_t)h * D_;
  const size_t kvb = (size_t)(b * H_ + h) * ((size_t)NSTEP * 4096);

  // Q fragments (B-operand of S^T): Q[qi][d = 32f + quad*8 + j], fp32 -> bf16 (once)
  short8 qf[4];
  {
    const float* qrow = Qp + bh + (size_t)qi * strideS;
#pragma unroll
    for (int f = 0; f < 4; ++f) {
      float4 a  = *(const float4*)(qrow + f * 32 + quad * 8);
      float4 bv = *(const float4*)(qrow + f * 32 + quad * 8 + 4);
      short8 r;
      r[0] = (short)f2bf(a.x);  r[1] = (short)f2bf(a.y);
      r[2] = (short)f2bf(a.z);  r[3] = (short)f2bf(a.w);
      r[4] = (short)f2bf(bv.x); r[5] = (short)f2bf(bv.y);
      r[6] = (short)f2bf(bv.z); r[7] = (short)f2bf(bv.w);
      qf[f] = r;
    }
  }

  const uint32_t* mrow = Mw + ((size_t)b * S_ + qi) * NSTEP;

  // --- block-valid step mask, computed once
  uint32_t myv = 0;
#pragma unroll
  for (int i = 0; i < 8; ++i) {
    uint4 v = *(const uint4*)(mrow + i * 4);
    myv |= (uint32_t)(v.x != 0) << (i * 4 + 0);
    myv |= (uint32_t)(v.y != 0) << (i * 4 + 1);
    myv |= (uint32_t)(v.z != 0) << (i * 4 + 2);
    myv |= (uint32_t)(v.w != 0) << (i * 4 + 3);
  }
  if (tid == 0) vmask_sh = 0;
  __syncthreads();
  {
    uint32_t wor = myv;
#pragma unroll
    for (int d = 1; d < 64; d <<= 1) wor |= __shfl_xor(wor, d);
    if (lane == 0) atomicOr(&vmask_sh, wor);
  }
  __syncthreads();
  const uint32_t bmask = vmask_sh;

  float m  = -INFINITY;
  float ll = 0.f;   // per-lane partial; cross-quad reduced ONCE in epilogue
  f32x4 acc[8];
#pragma unroll
  for (int t = 0; t < 8; ++t) acc[t] = (f32x4){0.f, 0.f, 0.f, 0.f};

  const float SL2E = 0.08838834764831845f * 1.4426950408889634f; // sm_scale * log2(e)

  auto stage = [&](int bufi, int stp) {
    const unsigned short* kg = Kw + kvb + (size_t)stp * 4096 + w * 1024 + lane * 8;
    const unsigned short* vg = Vw + kvb + (size_t)stp * 4096 + w * 1024 + lane * 8;
    unsigned short* kl = &klds[bufi][w * 1024];
    unsigned short* vl = &vlds[bufi][w * 1024];
    __builtin_amdgcn_global_load_lds(
        (const __attribute__((address_space(1))) void*)kg,
        (__attribute__((address_space(3))) void*)kl, 16, 0, 0);
    __builtin_amdgcn_global_load_lds(
        (const __attribute__((address_space(1))) void*)(kg + 512),
        (__attribute__((address_space(3))) void*)(kl + 512), 16, 0, 0);
    __builtin_amdgcn_global_load_lds(
        (const __attribute__((address_space(1))) void*)vg,
        (__attribute__((address_space(3))) void*)vl, 16, 0, 0);
    __builtin_amdgcn_global_load_lds(
        (const __attribute__((address_space(1))) void*)(vg + 512),
        (__attribute__((address_space(3))) void*)(vl + 512), 16, 0, 0);
  };

  int st  = bmask ? (__ffs(bmask) - 1) : -1;
  int cur = 0;
  uint32_t rem = bmask;
  uint32_t mw_ = 0;

  if (st >= 0) {
    mw_ = mrow[st];
    stage(0, st);
    asm volatile("s_waitcnt vmcnt(0)" ::: "memory");
    __builtin_amdgcn_s_barrier();
    asm volatile("" ::: "memory");
  }

  while (st >= 0) {
    rem &= rem - 1;
    const int nst = rem ? (__ffs(rem) - 1) : -1;

    // next mask word issued BEFORE the prefetch so its vmcnt wait (older) never
    // drains the 4 prefetch loads (newer).
    uint32_t mnxt = 0;
    if (nst >= 0) {
      mnxt = mrow[nst];
      stage(cur ^ 1, nst);   // prefetch next valid step; in flight during compute
    }

    const int m0 = (int)((mw_ >> (quad * 4)) & 15u);        // tile0 bits for my 4 keys
    const int m1 = (int)((mw_ >> (16 + quad * 4)) & 15u);   // tile1 bits
    const int wvv = __any(m0 | m1);

    if (wvv) {
      const unsigned short* kb_ = klds[cur];
      const unsigned short* vb_ = vlds[cur];

      f32x4 st0 = (f32x4){0.f, 0.f, 0.f, 0.f};
      f32x4 st1 = (f32x4){0.f, 0.f, 0.f, 0.f};
      __builtin_amdgcn_s_setprio(1);
#pragma unroll
      for (int f = 0; f < 4; ++f) {
        short8 ka  = *(const short8*)(kb_ + f * 1024 + lane * 8);
        short8 kbt = *(const short8*)(kb_ + f * 1024 + 512 + lane * 8);
        st0 = __builtin_amdgcn_mfma_f32_16x16x32_bf16(ka,  qf[f], st0, 0, 0, 0);
        st1 = __builtin_amdgcn_mfma_f32_16x16x32_bf16(kbt, qf[f], st1, 0, 0, 0);
      }
      __builtin_amdgcn_s_setprio(0);

      // logits in log2 domain; masked -> -inf (bias is exactly {0, -fp32max})
      float x0[4], x1[4];
      float mt = -INFINITY;
#pragma unroll
      for (int r = 0; r < 4; ++r) {
        x0[r] = ((m0 >> r) & 1) ? st0[r] * SL2E : -INFINITY;
        x1[r] = ((m1 >> r) & 1) ? st1[r] * SL2E : -INFINITY;
        mt = fmaxf(mt, fmaxf(x0[r], x1[r]));
      }
      mt = fmaxf(mt, __shfl_xor(mt, 16));
      mt = fmaxf(mt, __shfl_xor(mt, 32));   // per-query tile max (quad-uniform)

      // defer-max: only rescale when the tile max overtakes running max by >8
      if (!__all(mt <= m + 8.f)) {
        const float mn    = fmaxf(m, mt);
        const float alpha = exp2f(m - mn);   // quad-uniform per query
        m = mn;
        ll *= alpha;
#pragma unroll
        for (int t = 0; t < 8; ++t) {
          acc[t][0] *= alpha; acc[t][1] *= alpha;
          acc[t][2] *= alpha; acc[t][3] *= alpha;
        }
      }

      float p0[4], p1[4];
      float lt = 0.f;
#pragma unroll
      for (int r = 0; r < 4; ++r) {
        p0[r] = exp2f(x0[r] - m);   // bounded by 2^8 under defer
        p1[r] = exp2f(x1[r] - m);
        lt += p0[r] + p1[r];
      }
      ll += lt;   // per-lane partial (no per-step cross-quad reduce)

      // pack P^T to bf16 pairs with HW cvt_pk (lo = src0), then cross-quad shuffles
      int i0, i1, i2, i3;
      asm("v_cvt_pk_bf16_f32 %0, %1, %2" : "=v"(i0) : "v"(p0[0]), "v"(p0[1]));
      asm("v_cvt_pk_bf16_f32 %0, %1, %2" : "=v"(i1) : "v"(p0[2]), "v"(p0[3]));
      asm("v_cvt_pk_bf16_f32 %0, %1, %2" : "=v"(i2) : "v"(p1[0]), "v"(p1[1]));
      asm("v_cvt_pk_bf16_f32 %0, %1, %2" : "=v"(i3) : "v"(p1[2]), "v"(p1[3]));

      const int srcA = ((quad & 1) << 5) + c;
      const int srcB = srcA + 16;
      const int hiT  = quad >> 1;

      int sA, sB, w0, w1, w2, w3;
      sA = __shfl(i0, srcA); sB = __shfl(i2, srcA); w0 = hiT ? sB : sA;
      sA = __shfl(i1, srcA); sB = __shfl(i3, srcA); w1 = hiT ? sB : sA;
      sA = __shfl(i0, srcB); sB = __shfl(i2, srcB); w2 = hiT ? sB : sA;
      sA = __shfl(i1, srcB); sB = __shfl(i3, srcB); w3 = hiT ? sB : sA;

      union { int u[4]; short8 v; } pf;
      pf.u[0] = w0; pf.u[1] = w1; pf.u[2] = w2; pf.u[3] = w3;

      __builtin_amdgcn_s_setprio(1);
#pragma unroll
      for (int t = 0; t < 8; ++t) {
        short8 vf = *(const short8*)(vb_ + t * 512 + lane * 8);
        acc[t] = __builtin_amdgcn_mfma_f32_16x16x32_bf16(vf, pf.v, acc[t], 0, 0, 0);
      }
      __builtin_amdgcn_s_setprio(0);
    }

    if (nst >= 0) {
      // single trailing drain+barrier: prefetch completed while we computed;
      // also orders buf reuse (LDS reads above were lgkm-drained before MFMA).
      asm volatile("s_waitcnt vmcnt(0)" ::: "memory");
      __builtin_amdgcn_s_barrier();
      asm volatile("" ::: "memory");
    }
    cur ^= 1;
    st = nst;
    mw_ = mnxt;
  }

  // epilogue: reduce ll across quads once, then O[qi][d] = acc / l
  ll += __shfl_xor(ll, 16);
  ll += __shfl_xor(ll, 32);
  const float rl = 1.0f / ll;
  float* orow = Op + bh + (size_t)qi * strideS;
#pragma unroll
  for (int t = 0; t < 8; ++t) {
    float4 o;
    o.x = acc[t][0] * rl; o.y = acc[t][1] * rl;
    o.z = acc[t][2] * rl; o.w = acc[t][3] * rl;
    *(float4*)(orow + t * 16 + quad * 4) = o;
  }
}

// ---------------------------------------------------------------------------
// Fallback: previous verified kernel, used only if ws_size is too small.
// ---------------------------------------------------------------------------
__global__ __launch_bounds__(256, 2)
void fa_fwd(const float* __restrict__ Qp,
            const float* __restrict__ Kp,
            const float* __restrict__ Vp,
            const float* __restrict__ BiasP,
            float* __restrict__ Op)
{
  __shared__ __align__(16) unsigned short klds[32 * 136];
  __shared__ __align__(16) unsigned short vlds[8 * 520];

  const int tid  = threadIdx.x;
  const int lane = tid & 63;
  const int w    = tid >> 6;
  const int quad = lane >> 4;
  const int c    = lane & 15;

  const int qt = blockIdx.x;
  const int h  = blockIdx.y;
  const int b  = blockIdx.z;
  const int qi = qt * 64 + w * 16 + c;

  const size_t strideS = (size_t)H_ * D_;
  const size_t bh = ((size_t)b * S_) * strideS + (size_t)h * D_;

  short8 qf[4];
  {
    const float* qrow = Qp + bh + (size_t)qi * strideS;
#pragma unroll
    for (int f = 0; f < 4; ++f) {
      float4 a  = *(const float4*)(qrow + f * 32 + quad * 8);
      float4 bv = *(const float4*)(qrow + f * 32 + quad * 8 + 4);
      short8 r;
      r[0] = (short)f2bf(a.x);  r[1] = (short)f2bf(a.y);
      r[2] = (short)f2bf(a.z);  r[3] = (short)f2bf(a.w);
      r[4] = (short)f2bf(bv.x); r[5] = (short)f2bf(bv.y);
      r[6] = (short)f2bf(bv.z); r[7] = (short)f2bf(bv.w);
      qf[f] = r;
    }
  }

  const float* brow = BiasP + ((size_t)b * S_ + qi) * S_;
  const float NEGT = -1e37f;

  float m  = -INFINITY;
  float ll = 0.f;
  f32x4 acc[8];
#pragma unroll
  for (int t = 0; t < 8; ++t) acc[t] = (f32x4){0.f, 0.f, 0.f, 0.f};

  const float SL2E = 0.08838834764831845f * 1.4426950408889634f;
  const float L2E  = 1.4426950408889634f;

  for (int ks = 0; ks < S_; ks += 32) {
    float4 b0f = *(const float4*)(brow + ks + quad * 4);
    float4 b1f = *(const float4*)(brow + ks + 16 + quad * 4);
    float b0a[4] = {b0f.x, b0f.y, b0f.z, b0f.w};
    float b1a[4] = {b1f.x, b1f.y, b1f.z, b1f.w};
    int lv = 0;
#pragma unroll
    for (int r = 0; r < 4; ++r) lv |= (b0a[r] > NEGT) | (b1a[r] > NEGT);
    const int wv = __any(lv);
    const int bvalid = __syncthreads_or(wv);
    if (!bvalid) continue;

    {
      const int kk = tid >> 3;
      const int dc = tid & 7;

      const float* krow = Kp + bh + (size_t)(ks + kk) * strideS + dc * 16;
      unsigned short kb16[16];
#pragma unroll
      for (int i = 0; i < 4; ++i) {
        float4 kv = *(const float4*)(krow + i * 4);
        kb16[i*4+0] = f2bf(kv.x); kb16[i*4+1] = f2bf(kv.y);
        kb16[i*4+2] = f2bf(kv.z); kb16[i*4+3] = f2bf(kv.w);
      }
      usvec4* kdst = (usvec4*)(klds + kk * 136 + dc * 16);
#pragma unroll
      for (int i = 0; i < 4; ++i)
        kdst[i] = (usvec4){kb16[i*4+0], kb16[i*4+1], kb16[i*4+2], kb16[i*4+3]};

      const float* vrow = Vp + bh + (size_t)(ks + kk) * strideS + dc * 16;
      const int base = dc * 520 + (kk >> 3) * 128 + (kk & 7);
#pragma unroll
      for (int i = 0; i < 4; ++i) {
        float4 vv = *(const float4*)(vrow + i * 4);
        vlds[base + (i*4+0)*8] = f2bf(vv.x);
        vlds[base + (i*4+1)*8] = f2bf(vv.y);
        vlds[base + (i*4+2)*8] = f2bf(vv.z);
        vlds[base + (i*4+3)*8] = f2bf(vv.w);
      }
    }
    __syncthreads();

    if (wv) {
      f32x4 st0 = (f32x4){0.f, 0.f, 0.f, 0.f};
      f32x4 st1 = (f32x4){0.f, 0.f, 0.f, 0.f};
#pragma unroll
      for (int f = 0; f < 4; ++f) {
        short8 ka = *(const short8*)(klds + c * 136 + f * 32 + quad * 8);
        short8 kb = *(const short8*)(klds + (16 + c) * 136 + f * 32 + quad * 8);
        st0 = __builtin_amdgcn_mfma_f32_16x16x32_bf16(ka, qf[f], st0, 0, 0, 0);
        st1 = __builtin_amdgcn_mfma_f32_16x16x32_bf16(kb, qf[f], st1, 0, 0, 0);
      }

      float x0[4], x1[4];
      float mt = -INFINITY;
#pragma unroll
      for (int r = 0; r < 4; ++r) {
        x0[r] = (b0a[r] > NEGT) ? fmaf(b0a[r], L2E, st0[r] * SL2E) : -INFINITY;
        x1[r] = (b1a[r] > NEGT) ? fmaf(b1a[r], L2E, st1[r] * SL2E) : -INFINITY;
        mt = fmaxf(mt, fmaxf(x0[r], x1[r]));
      }
      mt = fmaxf(mt, __shfl_xor(mt, 16));
      mt = fmaxf(mt, __shfl_xor(mt, 32));
      const float mn    = fmaxf(m, mt);
      const float alpha = exp2f(m - mn);
      m = mn;

      float p0[4], p1[4];
      float lt = 0.f;
#pragma unroll
      for (int r = 0; r < 4; ++r) {
        p0[r] = exp2f(x0[r] - mn);
        p1[r] = exp2f(x1[r] - mn);
        lt += p0[r] + p1[r];
      }
      lt += __shfl_xor(lt, 16);
      lt += __shfl_xor(lt, 32);
      ll = ll * alpha + lt;

#pragma unroll
      for (int t = 0; t < 8; ++t) {
        acc[t][0] *= alpha; acc[t][1] *= alpha;
        acc[t][2] *= alpha; acc[t][3] *= alpha;
      }

      const int i0 = (int)(((uint32_t)f2bf(p0[0])) | ((uint32_t)f2bf(p0[1]) << 16));
      const int i1 = (int)(((uint32_t)f2bf(p0[2])) | ((uint32_t)f2bf(p0[3]) << 16));
      const int i2 = (int)(((uint32_t)f2bf(p1[0])) | ((uint32_t)f2bf(p1[1]) << 16));
      const int i3 = (int)(((uint32_t)f2bf(p1[2])) | ((uint32_t)f2bf(p1[3]) << 16));

      const int srcA = ((quad & 1) << 5) + c;
      const int srcB = srcA + 16;
      const int hiT  = quad >> 1;

      int sA, sB, w0, w1, w2, w3;
      sA = __shfl(i0, srcA); sB = __shfl(i2, srcA); w0 = hiT ? sB : sA;
      sA = __shfl(i1, srcA); sB = __shfl(i3, srcA); w1 = hiT ? sB : sA;
      sA = __shfl(i0, srcB); sB = __shfl(i2, srcB); w2 = hiT ? sB : sA;
      sA = __shfl(i1, srcB); sB = __shfl(i3, srcB); w3 = hiT ? sB : sA;

      union { int u[4]; short8 v; } pf;
      pf.u[0] = w0; pf.u[1] = w1; pf.u[2] = w2; pf.u[3] = w3;

#pragma unroll
      for (int t = 0; t < 8; ++t) {
        short8 vf = *(const short8*)(vlds + t * 520 + lane * 8);
        acc[t] = __builtin_amdgcn_mfma_f32_16x16x32_bf16(vf, pf.v, acc[t], 0, 0, 0);
      }
    }
    __syncthreads();
  }

  const float rl = 1.0f / ll;
  float* orow = Op + bh + (size_t)qi * strideS;
#pragma unroll
  for (int t = 0; t < 8; ++t) {
    float4 o;
    o.x = acc[t][0] * rl; o.y = acc[t][1] * rl;
    o.z = acc[t][2] * rl; o.w = acc[t][3] * rl;
    *(float4*)(orow + t * 16 + quad * 4) = o;
  }
}

extern "C" void kernel_launch(void* const* d_in, const int* in_sizes, int n_in,
                              void* d_out, int out_size, void* d_ws, size_t ws_size,
                              hipStream_t stream) {
  const float* q    = (const float*)d_in[0];
  const float* k    = (const float*)d_in[1];
  const float* v    = (const float*)d_in[2];
  const float* bias = (const float*)d_in[3];
  float* out = (float*)d_out;

  const size_t KW_BYTES = (size_t)B_ * H_ * NSTEP * 4096 * 2;  // 64 MiB (bf16 K frags)
  const size_t MW_BYTES = (size_t)B_ * S_ * NSTEP * 4;         // 1 MiB  (bias bitmask)
  const size_t SU_BYTES = (size_t)B_ * NSTEP * 4;              // 1 KiB  (step-used flags)
  const size_t NEED     = 2 * KW_BYTES + MW_BYTES + SU_BYTES;

  dim3 grid(S_ / 64, H_, B_);
  if (ws_size >= NEED) {
    unsigned short* Kw = (unsigned short*)d_ws;
    unsigned short* Vw = (unsigned short*)((char*)d_ws + KW_BYTES);
    uint32_t*       Mw = (uint32_t*)((char*)d_ws + 2 * KW_BYTES);
    uint32_t*       Su = (uint32_t*)((char*)d_ws + 2 * KW_BYTES + MW_BYTES);
    hipMemsetAsync(Su, 0, SU_BYTES, stream);
    mask_pre<<<(B_ * S_ * NSTEP) / 256, 256, 0, stream>>>(bias, Mw, Su);
    kv_pre<<<(B_ * H_ * NSTEP * 512) / 256, 256, 0, stream>>>(k, v, Kw, Vw, Su);
    fa_fwd2<<<grid, 256, 0, stream>>>(q, Kw, Vw, Mw, out);
  } else {
    fa_fwd<<<grid, 256, 0, stream>>>(q, k, v, bias, out);
  }
}